// Round 2
// baseline (30.717 us; speedup 1.0000x reference)
//
#include <hip/hip_runtime.h>

namespace {
constexpr int kB = 16;
constexpr int kG = 16384;
constexpr int kC = 8;
constexpr int kS = 8;
constexpr int kL = 4;
constexpr int kLogG = 14;   // G = 2^14
}

// x (B,G) -> xt (G,B): per-index gathers become one contiguous 64B line.
__global__ void xt_transpose(const float* __restrict__ x, float* __restrict__ xt) {
    const int g = blockIdx.x * blockDim.x + threadIdx.x;
    if (g >= kG) return;
    float v[kB];
#pragma unroll
    for (int b = 0; b < kB; ++b) v[b] = x[b * kG + g];   // coalesced per b
    float4* dst = reinterpret_cast<float4*>(xt + (size_t)g * kB);
#pragma unroll
    for (int j = 0; j < 4; ++j)
        dst[j] = make_float4(v[4 * j + 0], v[4 * j + 1], v[4 * j + 2], v[4 * j + 3]);
}

// Thread = (c, g, bq) with bq = quartet of batch rows. Lanes 0-3 of each
// 4-lane group share the same (c,g): identical int4 index load (one
// transaction) and their 4 float4 gathers tile the index's 64B line exactly.
template <bool USE_XT>
__global__ void clause_eval(const float* __restrict__ xsrc,
                            const int* __restrict__ idx,
                            float* __restrict__ out) {
    const int tid = blockIdx.x * blockDim.x + threadIdx.x;
    const int bq = tid & 3;          // batch quartet 0..3
    const int cg = tid >> 2;         // c*G + g
    const int g  = cg & (kG - 1);
    const int c  = cg >> kLogG;

    const int* ib = idx + (size_t)cg * (kS * kL);
    float4 acc = make_float4(0.f, 0.f, 0.f, 0.f);

#pragma unroll
    for (int s = 0; s < kS; ++s) {
        int4 iv = *reinterpret_cast<const int4*>(ib + s * kL);
        const int i0 = iv.x, i1 = iv.y, i2 = iv.z, i3 = iv.w;
        if constexpr (USE_XT) {
            const float* xb = xsrc + bq * 4;
            float4 a = *reinterpret_cast<const float4*>(xb + i0 * kB);
            float4 b = *reinterpret_cast<const float4*>(xb + i1 * kB);
            float4 e = *reinterpret_cast<const float4*>(xb + i2 * kB);
            float4 d = *reinterpret_cast<const float4*>(xb + i3 * kB);
            acc.x += a.x * b.x * e.x * d.x;
            acc.y += a.y * b.y * e.y * d.y;
            acc.z += a.z * b.z * e.z * d.z;
            acc.w += a.w * b.w * e.w * d.w;
        } else {
            float* accp = &acc.x;
#pragma unroll
            for (int j = 0; j < 4; ++j) {
                const float* row = xsrc + (size_t)(bq * 4 + j) * kG;
                accp[j] += row[i0] * row[i1] * row[i2] * row[i3];
            }
        }
    }

    float* ob = out + (size_t)c * (kB * kG) + (size_t)(bq * 4) * kG + g;
    ob[0 * kG] = acc.x;
    ob[1 * kG] = acc.y;
    ob[2 * kG] = acc.z;
    ob[3 * kG] = acc.w;
}

extern "C" void kernel_launch(void* const* d_in, const int* in_sizes, int n_in,
                              void* d_out, int out_size, void* d_ws, size_t ws_size,
                              hipStream_t stream) {
    const float* x = (const float*)d_in[0];
    const int* I = (const int*)d_in[1];
    float* out = (float*)d_out;

    const size_t xt_bytes = (size_t)kG * kB * sizeof(float);  // 1 MiB
    const int total = kC * kG * 4;        // 524288 threads
    const int block = 256;
    const int grid = total / block;       // 2048 blocks -> 8 blocks/CU

    if (ws_size >= xt_bytes) {
        float* xt = (float*)d_ws;
        xt_transpose<<<(kG + block - 1) / block, block, 0, stream>>>(x, xt);
        clause_eval<true><<<grid, block, 0, stream>>>(xt, I, out);
    } else {
        clause_eval<false><<<grid, block, 0, stream>>>(x, I, out);
    }
}

// Round 3
// 20.636 us; speedup vs baseline: 1.4885x; 1.4885x over previous
//
#include <hip/hip_runtime.h>

namespace {
constexpr int kB = 16;
constexpr int kG = 16384;
constexpr int kC = 8;
constexpr int kS = 8;
constexpr int kL = 4;
constexpr int kLogG = 14;     // G = 2^14
constexpr int kParts = 4;     // batch quads: b = part*4 + j
constexpr int kChunks = 64;   // cg-space chunks
constexpr int kCGPerChunk = (kC * kG) / kChunks;  // 2048
constexpr int kThreads = 512; // 128 lane-groups of 4 (s-split)
}

typedef _Float16 h4 __attribute__((ext_vector_type(4)));

// ---- prep: x (B,G) fp32 -> xh[part][g] = {x[4p+0..3, g]} as fp16x4 (512 KB)
__global__ void build_xh(const float* __restrict__ x, h4* __restrict__ xh) {
    const int g = blockIdx.x * blockDim.x + threadIdx.x;
    if (g >= kG) return;
#pragma unroll
    for (int p = 0; p < kParts; ++p) {
        h4 v;
#pragma unroll
        for (int j = 0; j < 4; ++j) v[j] = (_Float16)x[(p * 4 + j) * kG + g];
        xh[p * kG + g] = v;
    }
}

// ---- main: block = (chunk, part). LDS holds the part's full (G,4) fp16 slice.
// Within each 4-lane group: lanes share cg, split S (lane sq does s=sq, sq+4).
__global__ __launch_bounds__(kThreads) void clause_eval_lds(
        const h4* __restrict__ xh, const int* __restrict__ idx,
        float* __restrict__ out) {
    extern __shared__ h4 xs[];   // kG elems = 128 KB

    // bid -> (chunk, part) s.t. the 4 partition-siblings of a chunk share an XCD
    const int bid = blockIdx.x;
    const int xcd = bid & 7;
    const int slot = bid >> 3;          // 0..31
    const int part = slot & 3;
    const int chunk = (slot >> 2) * 8 + xcd;   // 0..63

    // stage 128 KB partition slice into LDS (linear, coalesced)
    {
        const float4* src = (const float4*)(xh + (size_t)part * kG);
        float4* dst = (float4*)xs;
#pragma unroll
        for (int i = 0; i < (kG * 8 / 16) / kThreads; ++i)   // 16 iters
            dst[i * kThreads + threadIdx.x] = src[i * kThreads + threadIdx.x];
    }
    __syncthreads();

    const int t = threadIdx.x;
    const int sq = t & 3;          // s-quarter: handles s=sq and s=sq+4
    const int gid = t >> 2;        // 0..127 (cg lane-group)
    const int cgbase = chunk * kCGPerChunk;
    const int4* ibase = (const int4*)idx;   // 8 int4 per cg

#pragma unroll 4
    for (int j = 0; j < kCGPerChunk / 128; ++j) {   // 16 cg per thread
        const int cg = cgbase + gid + j * 128;
        const int4* ip = ibase + (size_t)cg * kS;   // lanes 0-3 cover one 64B line
        const int4 a0 = ip[sq];
        const int4 a1 = ip[sq + 4];

        // products over l for 4 b's, from LDS (ds_read_b64 each)
        h4 p0 = xs[a0.x] * xs[a0.y] * xs[a0.z] * xs[a0.w];
        h4 p1 = xs[a1.x] * xs[a1.y] * xs[a1.z] * xs[a1.w];

        float4 v = make_float4((float)p0[0] + (float)p1[0],
                               (float)p0[1] + (float)p1[1],
                               (float)p0[2] + (float)p1[2],
                               (float)p0[3] + (float)p1[3]);

        // sum the 4 s-partials across the 4-lane group
        v.x += __shfl_xor(v.x, 1); v.y += __shfl_xor(v.y, 1);
        v.z += __shfl_xor(v.z, 1); v.w += __shfl_xor(v.w, 1);
        v.x += __shfl_xor(v.x, 2); v.y += __shfl_xor(v.y, 2);
        v.z += __shfl_xor(v.z, 2); v.w += __shfl_xor(v.w, 2);

        // lane sq writes b = part*4 + sq
        const float r = (sq == 0) ? v.x : (sq == 1) ? v.y : (sq == 2) ? v.z : v.w;
        const int c = cg >> kLogG;
        const int g = cg & (kG - 1);
        out[c * (kB * kG) + (part * 4 + sq) * kG + g] = r;
    }
}

// ---- fallback (fp32 exact, R2 kernel) if ws is too small ----
__global__ void clause_eval_gather(const float* __restrict__ x,
                                   const int* __restrict__ idx,
                                   float* __restrict__ out) {
    const int tid = blockIdx.x * blockDim.x + threadIdx.x;
    const int bq = tid & 3;
    const int cg = tid >> 2;
    const int g  = cg & (kG - 1);
    const int c  = cg >> kLogG;
    const int* ib = idx + (size_t)cg * (kS * kL);
    float4 acc = make_float4(0.f, 0.f, 0.f, 0.f);
#pragma unroll
    for (int s = 0; s < kS; ++s) {
        int4 iv = *reinterpret_cast<const int4*>(ib + s * kL);
        float* accp = &acc.x;
#pragma unroll
        for (int j = 0; j < 4; ++j) {
            const float* row = x + (size_t)(bq * 4 + j) * kG;
            accp[j] += row[iv.x] * row[iv.y] * row[iv.z] * row[iv.w];
        }
    }
    float* ob = out + (size_t)c * (kB * kG) + (size_t)(bq * 4) * kG + g;
    ob[0 * kG] = acc.x; ob[1 * kG] = acc.y; ob[2 * kG] = acc.z; ob[3 * kG] = acc.w;
}

extern "C" void kernel_launch(void* const* d_in, const int* in_sizes, int n_in,
                              void* d_out, int out_size, void* d_ws, size_t ws_size,
                              hipStream_t stream) {
    const float* x = (const float*)d_in[0];
    const int* I = (const int*)d_in[1];
    float* out = (float*)d_out;

    const size_t xh_bytes = (size_t)kParts * kG * sizeof(h4);  // 512 KiB

    if (ws_size >= xh_bytes) {
        h4* xh = (h4*)d_ws;
        build_xh<<<kG / 256, 256, 0, stream>>>(x, xh);
        const int grid = kChunks * kParts;       // 256 blocks (1 per CU)
        const size_t lds = (size_t)kG * sizeof(h4);  // 128 KiB dynamic
        clause_eval_lds<<<grid, kThreads, lds, stream>>>(xh, I, out);
    } else {
        const int total = kC * kG * 4;
        clause_eval_gather<<<total / 256, 256, 0, stream>>>(x, I, out);
    }
}

// Round 4
// 13.297 us; speedup vs baseline: 2.3101x; 1.5519x over previous
//
#include <hip/hip_runtime.h>

namespace {
constexpr int kB = 16;
constexpr int kG = 16384;
constexpr int kC = 8;
constexpr int kS = 8;
constexpr int kLogG = 14;     // G = 2^14
constexpr int kParts = 4;     // batch quads: b = part*4 + j
constexpr int kChunks = 64;   // cg-space chunks
constexpr int kCGPerChunk = (kC * kG) / kChunks;  // 2048
constexpr int kThreads = 1024;
}

typedef _Float16 h4 __attribute__((ext_vector_type(4)));

// quad_perm DPP move (VALU — keeps the cross-lane reduce off the LDS pipe)
template <int CTRL>
__device__ __forceinline__ float qperm(float x) {
    int r = __builtin_amdgcn_update_dpp(0, __builtin_bit_cast(int, x),
                                        CTRL, 0xF, 0xF, true);
    return __builtin_bit_cast(float, r);
}

// Block = (chunk, part). LDS holds the part's full (G, 4-batch) fp16 slice.
// 4-lane groups share one cg: lane sq handles s = {sq, sq+4}; the two int4
// index loads of a group tile the cg's two 64B I-lines exactly.
__global__ __launch_bounds__(kThreads) void clause_eval_lds(
        const float* __restrict__ x, const int* __restrict__ idx,
        float* __restrict__ out) {
    extern __shared__ h4 xs[];   // kG * 8 B = 128 KiB

    // bid -> (chunk, part): the 4 part-siblings of a chunk share an XCD (L2 reuse of I)
    const int bid = blockIdx.x;
    const int xcd = bid & 7;
    const int slot = bid >> 3;          // 0..31
    const int part = slot & 3;
    const int chunk = (slot >> 2) * 8 + xcd;   // 0..63

    const int t = threadIdx.x;

    // ---- fused staging: x rows [4p..4p+3] -> LDS as fp16x4 per g ----
#pragma unroll
    for (int pass = 0; pass < kG / (kThreads * 4); ++pass) {   // 4 passes
        const int g0 = (pass * kThreads + t) * 4;
        const float4 r0 = *(const float4*)(x + (part * 4 + 0) * kG + g0);
        const float4 r1 = *(const float4*)(x + (part * 4 + 1) * kG + g0);
        const float4 r2 = *(const float4*)(x + (part * 4 + 2) * kG + g0);
        const float4 r3 = *(const float4*)(x + (part * 4 + 3) * kG + g0);
        union { h4 h[2]; float4 f; } p0, p1;
        p0.h[0] = h4{(_Float16)r0.x, (_Float16)r1.x, (_Float16)r2.x, (_Float16)r3.x};
        p0.h[1] = h4{(_Float16)r0.y, (_Float16)r1.y, (_Float16)r2.y, (_Float16)r3.y};
        p1.h[0] = h4{(_Float16)r0.z, (_Float16)r1.z, (_Float16)r2.z, (_Float16)r3.z};
        p1.h[1] = h4{(_Float16)r0.w, (_Float16)r1.w, (_Float16)r2.w, (_Float16)r3.w};
        float4* dst = (float4*)(xs + g0);
        dst[0] = p0.f;      // ds_write_b128 x2, contiguous
        dst[1] = p1.f;
    }
    __syncthreads();

    const int sq = t & 3;            // s-quarter: handles s = sq, sq+4
    const int gid = t >> 2;          // 0..255 (cg lane-group)
    const int cgbase = chunk * kCGPerChunk;
    const int4* ibase = (const int4*)idx;   // 8 int4 per cg

#pragma unroll
    for (int j = 0; j < kCGPerChunk / (kThreads / 4); ++j) {   // 8 iters
        const int cg = cgbase + j * (kThreads / 4) + gid;
        const int4* ip = ibase + (size_t)cg * kS;
        const int4 a0 = ip[sq];
        const int4 a1 = ip[sq + 4];

        // clause-body products for 4 b's (ds_read_b64 per index)
        h4 q0 = xs[a0.x] * xs[a0.y] * xs[a0.z] * xs[a0.w];
        h4 q1 = xs[a1.x] * xs[a1.y] * xs[a1.z] * xs[a1.w];
        h4 q = q0 + q1;              // sum of this lane's two s
        float4 v = make_float4((float)q[0], (float)q[1], (float)q[2], (float)q[3]);

        // 4x4 transpose-reduce across the 4-lane group: lane sq ends with
        // comp sq summed over all 4 lanes. Pure VALU (DPP quad_perm).
        const bool hi2 = (sq & 2) != 0;
        float c0 = (hi2 ? v.z : v.x) + qperm<0x4E>(hi2 ? v.x : v.z);  // xor 2
        float c1 = (hi2 ? v.w : v.y) + qperm<0x4E>(hi2 ? v.y : v.w);
        const bool odd = (sq & 1) != 0;
        float r = (odd ? c1 : c0) + qperm<0xB1>(odd ? c0 : c1);       // xor 1

        const int c = cg >> kLogG;
        const int g = cg & (kG - 1);
        out[c * (kB * kG) + (part * 4 + sq) * kG + g] = r;
    }
}

extern "C" void kernel_launch(void* const* d_in, const int* in_sizes, int n_in,
                              void* d_out, int out_size, void* d_ws, size_t ws_size,
                              hipStream_t stream) {
    const float* x = (const float*)d_in[0];
    const int* I = (const int*)d_in[1];
    float* out = (float*)d_out;

    const int grid = kChunks * kParts;           // 256 blocks -> 1/CU
    const size_t lds = (size_t)kG * sizeof(h4);  // 128 KiB dynamic
    clause_eval_lds<<<grid, kThreads, lds, stream>>>(x, I, out);
}

// Round 5
// 13.199 us; speedup vs baseline: 2.3273x; 1.0074x over previous
//
#include <hip/hip_runtime.h>

namespace {
constexpr int kB = 16;
constexpr int kG = 16384;
constexpr int kC = 8;
constexpr int kS = 8;
constexpr int kLogG = 14;     // G = 2^14
constexpr int kChunks = 64;   // cg-space chunks
constexpr int kCGPerChunk = (kC * kG) / kChunks;  // 2048
constexpr int kThreads = 1024;
constexpr int kGroups = kThreads / 4;             // 256 cg lane-groups
constexpr int kIters = kCGPerChunk / kGroups;     // 8
}

typedef _Float16 h4 __attribute__((ext_vector_type(4)));

// quad_perm DPP move (VALU — keeps the cross-lane reduce off the LDS pipe)
template <int CTRL>
__device__ __forceinline__ float qperm(float x) {
    int r = __builtin_amdgcn_update_dpp(0, __builtin_bit_cast(int, x),
                                        CTRL, 0xF, 0xF, true);
    return __builtin_bit_cast(float, r);
}

// Block = (chunk, part). LDS holds the part's full (G, 4-batch) fp16 slice.
// 4-lane groups share one cg: lane sq handles s = {sq, sq+4}; the two int4
// index loads of a group tile the cg's two 64B I-lines exactly.
__global__ __launch_bounds__(kThreads) void clause_eval_lds(
        const float* __restrict__ x, const int* __restrict__ idx,
        float* __restrict__ out) {
    extern __shared__ h4 xs[];   // kG * 8 B = 128 KiB

    // bid -> (chunk, part): the 4 part-siblings of a chunk share an XCD (L2 reuse of I)
    const int bid = blockIdx.x;
    const int xcd = bid & 7;
    const int slot = bid >> 3;          // 0..31
    const int part = slot & 3;
    const int chunk = (slot >> 2) * 8 + xcd;   // 0..63

    const int t = threadIdx.x;
    const int sq = t & 3;            // s-quarter: handles s = sq, sq+4
    const int gid = t >> 2;          // 0..255 (cg lane-group)
    const int cgbase = chunk * kCGPerChunk;
    const int4* ibase = (const int4*)idx;      // 8 int4 per cg

    // ---- pre-barrier I-prefetch (iters 0,1): HBM latency hides under staging
    const size_t ib0 = (size_t)(cgbase + gid) * kS;
    int4 ca0 = ibase[ib0 + sq];
    int4 ca1 = ibase[ib0 + sq + 4];
    int4 na0 = ibase[ib0 + (size_t)kGroups * kS + sq];
    int4 na1 = ibase[ib0 + (size_t)kGroups * kS + sq + 4];

    // ---- fused staging: x rows [4p..4p+3] -> LDS as fp16x4 per g ----
#pragma unroll
    for (int pass = 0; pass < kG / (kThreads * 4); ++pass) {   // 4 passes
        const int g0 = (pass * kThreads + t) * 4;
        const float4 r0 = *(const float4*)(x + (part * 4 + 0) * kG + g0);
        const float4 r1 = *(const float4*)(x + (part * 4 + 1) * kG + g0);
        const float4 r2 = *(const float4*)(x + (part * 4 + 2) * kG + g0);
        const float4 r3 = *(const float4*)(x + (part * 4 + 3) * kG + g0);
        union { h4 h[2]; float4 f; } p0, p1;
        p0.h[0] = h4{(_Float16)r0.x, (_Float16)r1.x, (_Float16)r2.x, (_Float16)r3.x};
        p0.h[1] = h4{(_Float16)r0.y, (_Float16)r1.y, (_Float16)r2.y, (_Float16)r3.y};
        p1.h[0] = h4{(_Float16)r0.z, (_Float16)r1.z, (_Float16)r2.z, (_Float16)r3.z};
        p1.h[1] = h4{(_Float16)r0.w, (_Float16)r1.w, (_Float16)r2.w, (_Float16)r3.w};
        float4* dst = (float4*)(xs + g0);
        dst[0] = p0.f;      // ds_write_b128 x2, contiguous
        dst[1] = p1.f;
    }
    __syncthreads();

    // hoisted output addressing: within a chunk, c is constant and the store
    // address is linear in j (stride kGroups floats)
    const int c = chunk >> 3;                      // kCGPerChunk*8 == kG
    float* ob = out + c * (kB * kG) + (part * 4 + sq) * kG
                    + ((chunk & 7) * kCGPerChunk + gid);

#pragma unroll
    for (int j = 0; j < kIters; ++j) {
        const int4 b0 = ca0, b1 = ca1;
        ca0 = na0; ca1 = na1;
        if (j + 2 < kIters) {   // 2-deep rotating prefetch, all static regs
            const size_t ibn = ib0 + (size_t)(j + 2) * kGroups * kS;
            na0 = ibase[ibn + sq];
            na1 = ibase[ibn + sq + 4];
        }

        // clause-body products for 4 b's (ds_read_b64 per index)
        h4 q = xs[b0.x] * xs[b0.y] * xs[b0.z] * xs[b0.w]
             + xs[b1.x] * xs[b1.y] * xs[b1.z] * xs[b1.w];
        float4 v = make_float4((float)q[0], (float)q[1], (float)q[2], (float)q[3]);

        // 4x4 transpose-reduce across the 4-lane group (pure VALU, DPP)
        const bool hi2 = (sq & 2) != 0;
        float c0 = (hi2 ? v.z : v.x) + qperm<0x4E>(hi2 ? v.x : v.z);  // xor 2
        float c1 = (hi2 ? v.w : v.y) + qperm<0x4E>(hi2 ? v.y : v.w);
        const bool odd = (sq & 1) != 0;
        float r = (odd ? c1 : c0) + qperm<0xB1>(odd ? c0 : c1);       // xor 1

        ob[j * kGroups] = r;
    }
}

extern "C" void kernel_launch(void* const* d_in, const int* in_sizes, int n_in,
                              void* d_out, int out_size, void* d_ws, size_t ws_size,
                              hipStream_t stream) {
    const float* x = (const float*)d_in[0];
    const int* I = (const int*)d_in[1];
    float* out = (float*)d_out;

    const int grid = kChunks * 4;                // 256 blocks -> 1/CU
    const size_t lds = (size_t)kG * sizeof(h4);  // 128 KiB dynamic
    clause_eval_lds<<<grid, kThreads, lds, stream>>>(x, I, out);
}